// Round 10
// baseline (148.513 us; speedup 1.0000x reference)
//
#include <hip/hip_runtime.h>
#include <hip/hip_fp8.h>

typedef int   i32x4  __attribute__((ext_vector_type(4)));
typedef float f32x16 __attribute__((ext_vector_type(16)));

#define BS 4096
#define D 1024          // elements per row; also BYTES per row in fp8
#define M2 8192

#define BKB 64          // K bytes per K-tile
#define NKT 16          // K-tiles
#define NT2 32          // 256-tiles per dim
#define NBLK2 528       // upper-triangle 256-tiles (528 % 8 == 0)

// workspace layout (bytes)
#define OFF_Z      ((size_t)0)
#define OFF_SUMEXP ((size_t)M2 * D * 2)
#define OFF_POS    (OFF_SUMEXP + (size_t)M2 * 4)
#define OFF_DIO    (OFF_POS + (size_t)M2 * 4)
#define OFF_DJO    (OFF_DIO + (size_t)BS * 4)

static __device__ __forceinline__ void gload_lds16(const void* g, void* l) {
  __builtin_amdgcn_global_load_lds(
      (__attribute__((address_space(1))) void*)(uintptr_t)g,
      (__attribute__((address_space(3))) void*)(unsigned int)(uintptr_t)l,
      16, 0, 0);
}

// ---------------- kernel 1: normalize rows, emit fp8 Z, per-row dots, zero sumexp ----------------
__global__ __launch_bounds__(256) void prep_kernel(
    const float* __restrict__ zi, const float* __restrict__ zj,
    const float* __restrict__ zo, unsigned char* __restrict__ Z,
    float* __restrict__ dio, float* __restrict__ djo,
    float* __restrict__ sumexp) {
  const int r = blockIdx.x;
  const int tid = threadIdx.x;
  if (tid < 2) sumexp[2 * r + tid] = 0.f;
  const float4 vi = ((const float4*)(zi + (size_t)r * D))[tid];
  const float4 vj = ((const float4*)(zj + (size_t)r * D))[tid];
  const float4 vo = ((const float4*)(zo + (size_t)r * D))[tid];

  float s[5];
  s[0] = vi.x * vi.x + vi.y * vi.y + vi.z * vi.z + vi.w * vi.w;
  s[1] = vj.x * vj.x + vj.y * vj.y + vj.z * vj.z + vj.w * vj.w;
  s[2] = vo.x * vo.x + vo.y * vo.y + vo.z * vo.z + vo.w * vo.w;
  s[3] = vi.x * vo.x + vi.y * vo.y + vi.z * vo.z + vi.w * vo.w;
  s[4] = vj.x * vo.x + vj.y * vo.y + vj.z * vo.z + vj.w * vo.w;

#pragma unroll
  for (int k = 0; k < 5; ++k)
#pragma unroll
    for (int o = 32; o; o >>= 1) s[k] += __shfl_xor(s[k], o);

  __shared__ float red[4][5];
  const int w = tid >> 6, lane = tid & 63;
  if (lane == 0) {
#pragma unroll
    for (int k = 0; k < 5; ++k) red[w][k] = s[k];
  }
  __syncthreads();
  float tot[5];
#pragma unroll
  for (int k = 0; k < 5; ++k)
    tot[k] = red[0][k] + red[1][k] + red[2][k] + red[3][k];

  const float rsi = 1.0f / sqrtf(tot[0]);
  const float rsj = 1.0f / sqrtf(tot[1]);
  const float rso = 1.0f / sqrtf(tot[2]);

  uchar4 oi, oj;
  oi.x = __hip_fp8_e4m3(vi.x * rsi).__x;
  oi.y = __hip_fp8_e4m3(vi.y * rsi).__x;
  oi.z = __hip_fp8_e4m3(vi.z * rsi).__x;
  oi.w = __hip_fp8_e4m3(vi.w * rsi).__x;
  oj.x = __hip_fp8_e4m3(vj.x * rsj).__x;
  oj.y = __hip_fp8_e4m3(vj.y * rsj).__x;
  oj.z = __hip_fp8_e4m3(vj.z * rsj).__x;
  oj.w = __hip_fp8_e4m3(vj.w * rsj).__x;
  ((uchar4*)(Z + (size_t)r * D))[tid] = oi;
  ((uchar4*)(Z + (size_t)(BS + r) * D))[tid] = oj;

  if (tid == 0) {
    dio[r] = tot[3] * rsi * rso;
    djo[r] = tot[4] * rsj * rso;
  }
}

// ---------------- kernel 2: 256^2 tiles, fp8 32x32x16, 4-phase counted-vmcnt schedule ----------------
// 8 waves (2x4), wave-tile 128x64. K-tile = 64 B, 4 phases/K-tile (quadrants with A held 2 phases,
// B re-read once). Staging: 4 row-halves per K-tile (Aa, Ba, Ab, Bb), one per phase, 1 gload/thread.
// Counted vmcnt: (1) at end-p0, (2) at end-p3 (per-wave units; stage = 1 vmem instr/wave).
__global__ __launch_bounds__(512, 2) void gemm_lse_kernel(
    const unsigned char* __restrict__ Z,
    float* __restrict__ sumexp, float* __restrict__ pos) {
  __shared__ __align__(16) unsigned char lA[2][256 * BKB];   // 2 x 16 KB
  __shared__ __align__(16) unsigned char lB[2][256 * BKB];
  __shared__ float psumR[4][256];
  __shared__ float psumC[2][256];

  // XCD-bijective swizzle (528 = 8 * 66)
  const int torig = blockIdx.x;
  const int t = (torig & 7) * (NBLK2 / 8) + (torig >> 3);

  // triangular decode over 32x32 tile grid: cum(bm) = bm*(65-bm)/2
  int bm = 0;
  while ((bm + 1) * (65 - (bm + 1)) / 2 <= t) ++bm;
  const int bn = bm + (t - bm * (65 - bm) / 2);
  const bool isDiag = (bm == bn);

  const int tid = threadIdx.x;
  const int lane = tid & 63, w = tid >> 6;       // 8 waves
  const int wr = w >> 2, wc = w & 3;             // 2 x 4
  const int l31 = lane & 31, lh = lane >> 5;

  // ---- staging maps (both-sides swizzle: LDS chunk p of row r holds global chunk p ^ ((r>>1)&3))
  const int rIdx = tid >> 2;                     // 0..127
  const int rAa = rIdx + ((tid >= 256) ? 64 : 0);            // rows {0-63, 128-191}
  const int rAb = rAa + 64;                                   // rows {64-127, 192-255}
  const int rBa = (rIdx & 31) + (tid >> 7) * 64;             // rows {g*64 + 0..31}
  const int rBb = rBa + 32;                                   // rows {g*64 + 32..63}
  const int dAa = tid * 16 + ((tid >= 256) ? 4096 : 0);
  const int dAb = dAa + 4096;
  const int dBa = tid * 16 + (tid >> 7) * 2048;
  const int dBb = dBa + 2048;
  const unsigned char* pAa = Z + (size_t)(bm * 256 + rAa) * D + ((tid & 3) ^ ((rAa >> 1) & 3)) * 16;
  const unsigned char* pAb = Z + (size_t)(bm * 256 + rAb) * D + ((tid & 3) ^ ((rAb >> 1) & 3)) * 16;
  const unsigned char* pBa = Z + (size_t)(bn * 256 + rBa) * D + ((tid & 3) ^ ((rBa >> 1) & 3)) * 16;
  const unsigned char* pBb = Z + (size_t)(bn * 256 + rBb) * D + ((tid & 3) ^ ((rBb >> 1) & 3)) * 16;

#define ST_AA(buf) do { gload_lds16(pAa, &lA[buf][dAa]); pAa += BKB; } while (0)
#define ST_AB(buf) do { gload_lds16(pAb, &lA[buf][dAb]); pAb += BKB; } while (0)
#define ST_BA(buf) do { gload_lds16(pBa, &lB[buf][dBa]); pBa += BKB; } while (0)
#define ST_BB(buf) do { gload_lds16(pBb, &lB[buf][dBb]); pBb += BKB; } while (0)

  // ---- read offsets (loop-invariant): row's bytes [lh*32,+32) as two swizzled 16B chunks
  int offA[4][2], offB[2][2];
#pragma unroll
  for (int mi = 0; mi < 4; ++mi) {
    const int rA = wr * 128 + mi * 32 + l31;
    const int key = (rA >> 1) & 3;
    offA[mi][0] = rA * BKB + ((lh * 2) ^ key) * 16;
    offA[mi][1] = rA * BKB + ((lh * 2 + 1) ^ key) * 16;
  }
#pragma unroll
  for (int ni = 0; ni < 2; ++ni) {
    const int rB = wc * 64 + ni * 32 + l31;
    const int key = (rB >> 1) & 3;
    offB[ni][0] = rB * BKB + ((lh * 2) ^ key) * 16;
    offB[ni][1] = rB * BKB + ((lh * 2 + 1) ^ key) * 16;
  }

  union U { i32x4 v; long l[2]; };
  f32x16 c00 = {}, c01 = {}, c10 = {}, c11 = {};
  f32x16 c20 = {}, c21 = {}, c30 = {}, c31 = {};

#define SBAR() __builtin_amdgcn_sched_barrier(0)
#define BAR()  __builtin_amdgcn_s_barrier()

#define MFMA8(cL, cH, a0, a1, b0, b1)                                              \
  do {                                                                             \
    cL = __builtin_amdgcn_mfma_f32_32x32x16_fp8_fp8(a0.l[0], b0.l[0], cL, 0,0,0);  \
    cH = __builtin_amdgcn_mfma_f32_32x32x16_fp8_fp8(a1.l[0], b0.l[0], cH, 0,0,0);  \
    cL = __builtin_amdgcn_mfma_f32_32x32x16_fp8_fp8(a0.l[1], b0.l[1], cL, 0,0,0);  \
    cH = __builtin_amdgcn_mfma_f32_32x32x16_fp8_fp8(a1.l[1], b0.l[1], cH, 0,0,0);  \
    cL = __builtin_amdgcn_mfma_f32_32x32x16_fp8_fp8(a0.l[2], b1.l[0], cL, 0,0,0);  \
    cH = __builtin_amdgcn_mfma_f32_32x32x16_fp8_fp8(a1.l[2], b1.l[0], cH, 0,0,0);  \
    cL = __builtin_amdgcn_mfma_f32_32x32x16_fp8_fp8(a0.l[3], b1.l[1], cL, 0,0,0);  \
    cH = __builtin_amdgcn_mfma_f32_32x32x16_fp8_fp8(a1.l[3], b1.l[1], cH, 0,0,0);  \
  } while (0)

  // A operand: per row two U's -> 4 longs (K-slots). Pack as Ux{lo16B,hi16B} -> l[0..3] via two U.
  // We use aXc0.v, aXc1.v; slots: c0.l[0], c0.l[1], c1.l[0], c1.l[1]. Wrap in a 4-long view:
  struct A4 { long l[4]; };

  // prologue: stage all 4 halves of tile 0
  ST_AA(0); ST_BA(0); ST_AB(0); ST_BB(0);
  asm volatile("s_waitcnt vmcnt(2)");   // Aa0, Ba0 retired
  BAR(); SBAR();

  for (int kt = 0; kt < NKT; ++kt) {
    const int cur = kt & 1, nxt = cur ^ 1;
    const unsigned char* Abase = &lA[cur][0];
    const unsigned char* Bbase = &lB[cur][0];
    const bool more = (kt + 1 < NKT);

    A4 a0, a1; U b0, b1, tmp0, tmp1;

    // ===== phase 0: read A(mi0,mi1)+B(ni0); stage Aa(next); MFMA c00,c10
    tmp0.v = *(const i32x4*)(Abase + offA[0][0]); tmp1.v = *(const i32x4*)(Abase + offA[0][1]);
    a0.l[0] = tmp0.l[0]; a0.l[1] = tmp0.l[1]; a0.l[2] = tmp1.l[0]; a0.l[3] = tmp1.l[1];
    tmp0.v = *(const i32x4*)(Abase + offA[1][0]); tmp1.v = *(const i32x4*)(Abase + offA[1][1]);
    a1.l[0] = tmp0.l[0]; a1.l[1] = tmp0.l[1]; a1.l[2] = tmp1.l[0]; a1.l[3] = tmp1.l[1];
    b0.v = *(const i32x4*)(Bbase + offB[0][0]); b1.v = *(const i32x4*)(Bbase + offB[0][1]);
    if (more) ST_AA(nxt);
    SBAR(); BAR();
    __builtin_amdgcn_s_setprio(1);
    {
      U a0lo, a0hi, a1lo, a1hi;
      a0lo.l[0] = a0.l[0]; a0lo.l[1] = a0.l[1]; a0hi.l[0] = a0.l[2]; a0hi.l[1] = a0.l[3];
      a1lo.l[0] = a1.l[0]; a1lo.l[1] = a1.l[1]; a1hi.l[0] = a1.l[2]; a1hi.l[1] = a1.l[3];
      c00 = __builtin_amdgcn_mfma_f32_32x32x16_fp8_fp8(a0.l[0], b0.l[0], c00, 0,0,0);
      c10 = __builtin_amdgcn_mfma_f32_32x32x16_fp8_fp8(a1.l[0], b0.l[0], c10, 0,0,0);
      c00 = __builtin_amdgcn_mfma_f32_32x32x16_fp8_fp8(a0.l[1], b0.l[1], c00, 0,0,0);
      c10 = __builtin_amdgcn_mfma_f32_32x32x16_fp8_fp8(a1.l[1], b0.l[1], c10, 0,0,0);
      c00 = __builtin_amdgcn_mfma_f32_32x32x16_fp8_fp8(a0.l[2], b1.l[0], c00, 0,0,0);
      c10 = __builtin_amdgcn_mfma_f32_32x32x16_fp8_fp8(a1.l[2], b1.l[0], c10, 0,0,0);
      c00 = __builtin_amdgcn_mfma_f32_32x32x16_fp8_fp8(a0.l[3], b1.l[1], c00, 0,0,0);
      c10 = __builtin_amdgcn_mfma_f32_32x32x16_fp8_fp8(a1.l[3], b1.l[1], c10, 0,0,0);
    }
    __builtin_amdgcn_s_setprio(0);
    SBAR();
    if (more) asm volatile("s_waitcnt vmcnt(1)");   // Bb(cur tile) retired; Aa(next) may fly
    else      asm volatile("s_waitcnt vmcnt(0)");
    BAR(); SBAR();

    // ===== phase 1: read B(ni1); stage Ba(next); MFMA c01,c11 (A held)
    b0.v = *(const i32x4*)(Bbase + offB[1][0]); b1.v = *(const i32x4*)(Bbase + offB[1][1]);
    if (more) ST_BA(nxt);
    SBAR(); BAR();
    __builtin_amdgcn_s_setprio(1);
    c01 = __builtin_amdgcn_mfma_f32_32x32x16_fp8_fp8(a0.l[0], b0.l[0], c01, 0,0,0);
    c11 = __builtin_amdgcn_mfma_f32_32x32x16_fp8_fp8(a1.l[0], b0.l[0], c11, 0,0,0);
    c01 = __builtin_amdgcn_mfma_f32_32x32x16_fp8_fp8(a0.l[1], b0.l[1], c01, 0,0,0);
    c11 = __builtin_amdgcn_mfma_f32_32x32x16_fp8_fp8(a1.l[1], b0.l[1], c11, 0,0,0);
    c01 = __builtin_amdgcn_mfma_f32_32x32x16_fp8_fp8(a0.l[2], b1.l[0], c01, 0,0,0);
    c11 = __builtin_amdgcn_mfma_f32_32x32x16_fp8_fp8(a1.l[2], b1.l[0], c11, 0,0,0);
    c01 = __builtin_amdgcn_mfma_f32_32x32x16_fp8_fp8(a0.l[3], b1.l[1], c01, 0,0,0);
    c11 = __builtin_amdgcn_mfma_f32_32x32x16_fp8_fp8(a1.l[3], b1.l[1], c11, 0,0,0);
    __builtin_amdgcn_s_setprio(0);
    SBAR(); BAR(); SBAR();

    // ===== phase 2: read A(mi2,mi3)+B(ni0 re-read); stage Ab(next); MFMA c20,c30
    tmp0.v = *(const i32x4*)(Abase + offA[2][0]); tmp1.v = *(const i32x4*)(Abase + offA[2][1]);
    a0.l[0] = tmp0.l[0]; a0.l[1] = tmp0.l[1]; a0.l[2] = tmp1.l[0]; a0.l[3] = tmp1.l[1];
    tmp0.v = *(const i32x4*)(Abase + offA[3][0]); tmp1.v = *(const i32x4*)(Abase + offA[3][1]);
    a1.l[0] = tmp0.l[0]; a1.l[1] = tmp0.l[1]; a1.l[2] = tmp1.l[0]; a1.l[3] = tmp1.l[1];
    b0.v = *(const i32x4*)(Bbase + offB[0][0]); b1.v = *(const i32x4*)(Bbase + offB[0][1]);
    if (more) ST_AB(nxt);
    SBAR(); BAR();
    __builtin_amdgcn_s_setprio(1);
    c20 = __builtin_amdgcn_mfma_f32_32x32x16_fp8_fp8(a0.l[0], b0.l[0], c20, 0,0,0);
    c30 = __builtin_amdgcn_mfma_f32_32x32x16_fp8_fp8(a1.l[0], b0.l[0], c30, 0,0,0);
    c20 = __builtin_amdgcn_mfma_f32_32x32x16_fp8_fp8(a0.l[1], b0.l[1], c20, 0,0,0);
    c30 = __builtin_amdgcn_mfma_f32_32x32x16_fp8_fp8(a1.l[1], b0.l[1], c30, 0,0,0);
    c20 = __builtin_amdgcn_mfma_f32_32x32x16_fp8_fp8(a0.l[2], b1.l[0], c20, 0,0,0);
    c30 = __builtin_amdgcn_mfma_f32_32x32x16_fp8_fp8(a1.l[2], b1.l[0], c30, 0,0,0);
    c20 = __builtin_amdgcn_mfma_f32_32x32x16_fp8_fp8(a0.l[3], b1.l[1], c20, 0,0,0);
    c30 = __builtin_amdgcn_mfma_f32_32x32x16_fp8_fp8(a1.l[3], b1.l[1], c30, 0,0,0);
    __builtin_amdgcn_s_setprio(0);
    SBAR(); BAR(); SBAR();

    // ===== phase 3: read B(ni1 re-read); stage Bb(next); MFMA c21,c31
    b0.v = *(const i32x4*)(Bbase + offB[1][0]); b1.v = *(const i32x4*)(Bbase + offB[1][1]);
    if (more) ST_BB(nxt);
    SBAR(); BAR();
    __builtin_amdgcn_s_setprio(1);
    c21 = __builtin_amdgcn_mfma_f32_32x32x16_fp8_fp8(a0.l[0], b0.l[0], c21, 0,0,0);
    c31 = __builtin_amdgcn_mfma_f32_32x32x16_fp8_fp8(a1.l[0], b0.l[0], c31, 0,0,0);
    c21 = __builtin_amdgcn_mfma_f32_32x32x16_fp8_fp8(a0.l[1], b0.l[1], c21, 0,0,0);
    c31 = __builtin_amdgcn_mfma_f32_32x32x16_fp8_fp8(a1.l[1], b0.l[1], c31, 0,0,0);
    c21 = __builtin_amdgcn_mfma_f32_32x32x16_fp8_fp8(a0.l[2], b1.l[0], c21, 0,0,0);
    c31 = __builtin_amdgcn_mfma_f32_32x32x16_fp8_fp8(a1.l[2], b1.l[0], c31, 0,0,0);
    c21 = __builtin_amdgcn_mfma_f32_32x32x16_fp8_fp8(a0.l[3], b1.l[1], c21, 0,0,0);
    c31 = __builtin_amdgcn_mfma_f32_32x32x16_fp8_fp8(a1.l[3], b1.l[1], c31, 0,0,0);
    __builtin_amdgcn_s_setprio(0);
    SBAR();
    if (more) { asm volatile("s_waitcnt vmcnt(2)"); }  // Aa,Ba(next) retired; Ab,Bb(next) fly
    BAR(); SBAR();
  }
#undef ST_AA
#undef ST_AB
#undef ST_BA
#undef ST_BB

  // ---- epilogue: 32x32 C layout (verified): col = l31, row = (r&3)+8*(r>>2)+4*lh
  const int brow = bm * 256, bcol = bn * 256;
  float cs0 = 0.f, cs1 = 0.f;
#pragma unroll
  for (int mi = 0; mi < 4; ++mi) {
#pragma unroll
    for (int r = 0; r < 16; ++r) {
      const int rit = (r & 3) + 8 * (r >> 2) + 4 * lh;
      const int gq = brow + wr * 128 + mi * 32 + rit;
      const int prt = gq ^ BS;
      float sse = 0.f;
#pragma unroll
      for (int ni = 0; ni < 2; ++ni) {
        const int gc = bcol + wc * 64 + ni * 32 + l31;
        const float v =
            (mi == 0) ? (ni == 0 ? c00[r] : c01[r]) :
            (mi == 1) ? (ni == 0 ? c10[r] : c11[r]) :
            (mi == 2) ? (ni == 0 ? c20[r] : c21[r]) :
                        (ni == 0 ? c30[r] : c31[r]);
        if (gc == prt) { pos[gq] = v; pos[gc] = v; }   // symmetric positive pair
        const float e = (gc != gq) ? __expf(v) : 0.f;  // exclude self-term
        sse += e;
        if (ni == 0) cs0 += e; else cs1 += e;
      }
      sse += __shfl_xor(sse, 1);
      sse += __shfl_xor(sse, 2);
      sse += __shfl_xor(sse, 4);
      sse += __shfl_xor(sse, 8);
      sse += __shfl_xor(sse, 16);
      if (l31 == 0) psumR[wc][wr * 128 + mi * 32 + rit] = sse;
    }
  }
  cs0 += __shfl_xor(cs0, 32);
  cs1 += __shfl_xor(cs1, 32);
  if (lh == 0) {
    psumC[wr][wc * 64 + l31] = cs0;
    psumC[wr][wc * 64 + 32 + l31] = cs1;
  }
  __syncthreads();
  if (tid < 256) {
    atomicAdd(&sumexp[brow + tid],
              psumR[0][tid] + psumR[1][tid] + psumR[2][tid] + psumR[3][tid]);
    if (!isDiag)
      atomicAdd(&sumexp[bcol + tid], psumC[0][tid] + psumC[1][tid]);
  }
}

// ---------------- kernel 3: final reduction + KL ----------------
__global__ __launch_bounds__(256) void finalize_kernel(
    const float* __restrict__ sumexp, const float* __restrict__ pos,
    const float* __restrict__ dio, const float* __restrict__ djo,
    float* __restrict__ out) {
  const int tid = threadIdx.x;
  float s1 = 0.f, sa = 0.f, sb = 0.f;
  for (int q = tid; q < M2; q += 256) s1 += __logf(sumexp[q]) - pos[q];
  for (int r = tid; r < BS; r += 256) { sa += __expf(dio[r]); sb += __expf(djo[r]); }

  __shared__ float red[4][3];
  float v3[3] = {s1, sa, sb};
#pragma unroll
  for (int k = 0; k < 3; ++k)
#pragma unroll
    for (int o = 32; o; o >>= 1) v3[k] += __shfl_xor(v3[k], o);
  const int w = tid >> 6, lane = tid & 63;
  if (lane == 0) { red[w][0] = v3[0]; red[w][1] = v3[1]; red[w][2] = v3[2]; }
  __syncthreads();
  const float S1 = red[0][0] + red[1][0] + red[2][0] + red[3][0];
  const float A  = red[0][1] + red[1][1] + red[2][1] + red[3][1];
  const float B  = red[0][2] + red[1][2] + red[2][2] + red[3][2];
  const float logB = __logf(B);
  const float invA = 1.0f / A;

  float kl = 0.f;
  for (int r = tid; r < BS; r += 256) {
    const float lp = djo[r] - logB;            // log_softmax target
    kl += __expf(lp) * (lp - __expf(dio[r]) * invA);
  }
#pragma unroll
  for (int o = 32; o; o >>= 1) kl += __shfl_xor(kl, o);
  __shared__ float red2[4];
  if (lane == 0) red2[w] = kl;
  __syncthreads();
  if (tid == 0) {
    const float KL = red2[0] + red2[1] + red2[2] + red2[3];
    out[0] = S1 / (float)M2 + 0.5f * KL;
  }
}

extern "C" void kernel_launch(void* const* d_in, const int* in_sizes, int n_in,
                              void* d_out, int out_size, void* d_ws, size_t ws_size,
                              hipStream_t stream) {
  const float* zi = (const float*)d_in[0];
  const float* zj = (const float*)d_in[1];
  const float* zo = (const float*)d_in[2];
  char* ws = (char*)d_ws;
  unsigned char* Z = (unsigned char*)(ws + OFF_Z);
  float* sumexp = (float*)(ws + OFF_SUMEXP);
  float* pos    = (float*)(ws + OFF_POS);
  float* dio    = (float*)(ws + OFF_DIO);
  float* djo    = (float*)(ws + OFF_DJO);

  prep_kernel<<<BS, 256, 0, stream>>>(zi, zj, zo, Z, dio, djo, sumexp);
  gemm_lse_kernel<<<NBLK2, 512, 0, stream>>>(Z, sumexp, pos);
  finalize_kernel<<<1, 256, 0, stream>>>(sumexp, pos, dio, djo, (float*)d_out);
}

// Round 11
// 107.758 us; speedup vs baseline: 1.3782x; 1.3782x over previous
//
#include <hip/hip_runtime.h>
#include <hip/hip_fp8.h>

typedef int   i32x4  __attribute__((ext_vector_type(4)));
typedef float f32x16 __attribute__((ext_vector_type(16)));

#define BS 4096
#define D 1024          // elements per row; also BYTES per row in fp8
#define M2 8192

#define BK 64           // K elements (= bytes) per K-step
#define NKT (D / BK)    // 16 K-steps
#define NT 64           // M2/128 tiles per dim
#define NBLK (NT * (NT + 1) / 2)   // 2080 upper-triangle blocks (2080 % 8 == 0)

// workspace layout (bytes)
#define OFF_Z      ((size_t)0)
#define OFF_SUMEXP ((size_t)M2 * D * 2)
#define OFF_POS    (OFF_SUMEXP + (size_t)M2 * 4)
#define OFF_DIO    (OFF_POS + (size_t)M2 * 4)
#define OFF_DJO    (OFF_DIO + (size_t)BS * 4)

static __device__ __forceinline__ void gload_lds16(const void* g, void* l) {
  __builtin_amdgcn_global_load_lds(
      (__attribute__((address_space(1))) void*)(uintptr_t)g,
      (__attribute__((address_space(3))) void*)(unsigned int)(uintptr_t)l,
      16, 0, 0);
}

// ---------------- kernel 1: normalize rows, emit fp8 Z, per-row dots, zero sumexp ----------------
__global__ __launch_bounds__(256) void prep_kernel(
    const float* __restrict__ zi, const float* __restrict__ zj,
    const float* __restrict__ zo, unsigned char* __restrict__ Z,
    float* __restrict__ dio, float* __restrict__ djo,
    float* __restrict__ sumexp) {
  const int r = blockIdx.x;
  const int tid = threadIdx.x;
  if (tid < 2) sumexp[2 * r + tid] = 0.f;
  const float4 vi = ((const float4*)(zi + (size_t)r * D))[tid];
  const float4 vj = ((const float4*)(zj + (size_t)r * D))[tid];
  const float4 vo = ((const float4*)(zo + (size_t)r * D))[tid];

  float s[5];
  s[0] = vi.x * vi.x + vi.y * vi.y + vi.z * vi.z + vi.w * vi.w;
  s[1] = vj.x * vj.x + vj.y * vj.y + vj.z * vj.z + vj.w * vj.w;
  s[2] = vo.x * vo.x + vo.y * vo.y + vo.z * vo.z + vo.w * vo.w;
  s[3] = vi.x * vo.x + vi.y * vo.y + vi.z * vo.z + vi.w * vo.w;
  s[4] = vj.x * vo.x + vj.y * vo.y + vj.z * vo.z + vj.w * vo.w;

#pragma unroll
  for (int k = 0; k < 5; ++k)
#pragma unroll
    for (int o = 32; o; o >>= 1) s[k] += __shfl_xor(s[k], o);

  __shared__ float red[4][5];
  const int w = tid >> 6, lane = tid & 63;
  if (lane == 0) {
#pragma unroll
    for (int k = 0; k < 5; ++k) red[w][k] = s[k];
  }
  __syncthreads();
  float tot[5];
#pragma unroll
  for (int k = 0; k < 5; ++k)
    tot[k] = red[0][k] + red[1][k] + red[2][k] + red[3][k];

  const float rsi = 1.0f / sqrtf(tot[0]);
  const float rsj = 1.0f / sqrtf(tot[1]);
  const float rso = 1.0f / sqrtf(tot[2]);

  uchar4 oi, oj;
  oi.x = __hip_fp8_e4m3(vi.x * rsi).__x;
  oi.y = __hip_fp8_e4m3(vi.y * rsi).__x;
  oi.z = __hip_fp8_e4m3(vi.z * rsi).__x;
  oi.w = __hip_fp8_e4m3(vi.w * rsi).__x;
  oj.x = __hip_fp8_e4m3(vj.x * rsj).__x;
  oj.y = __hip_fp8_e4m3(vj.y * rsj).__x;
  oj.z = __hip_fp8_e4m3(vj.z * rsj).__x;
  oj.w = __hip_fp8_e4m3(vj.w * rsj).__x;
  ((uchar4*)(Z + (size_t)r * D))[tid] = oi;
  ((uchar4*)(Z + (size_t)(BS + r) * D))[tid] = oj;

  if (tid == 0) {
    dio[r] = tot[3] * rsi * rso;
    djo[r] = tot[4] * rsj * rso;
  }
}

// ---------------- kernel 2: upper-triangle S = Z Z^T, fp8 32x32x16, ONE barrier/K-step ----------------
// 128x128 tile, 4 waves as 2x2, wave-tile 64x64 = 2x2 of 32x32, 4 K-slices per K-step (BK=64).
// 3 buffers + stage-depth-1 + vmcnt(0)-before-barrier:
//   iter kt: STAGE(kt+1 -> buf (kt+1)%3); ds_read buf[kt%3]; MFMA; vmcnt(0); BAR.
// Safety: at every barrier arrival each wave's stage of kt+1 is retired (vmcnt(0)), so
// post-barrier reads of buf[(kt+1)%3] are safe across waves; under 1-iter drift a leader
// at kt+1 stages (kt+2)%3 while a laggard reads kt%3 — distinct mod 3. LDS stays 51 KB
// (3 blocks/CU — the r9 4-buffer variant lost this and regressed).
__global__ __launch_bounds__(256) void gemm_lse_kernel(
    const unsigned char* __restrict__ Z,
    float* __restrict__ sumexp, float* __restrict__ pos) {
  __shared__ __align__(16) unsigned char lA[3][128 * BK];   // 3 x 8 KB
  __shared__ __align__(16) unsigned char lB[3][128 * BK];
  __shared__ float psumR[2][128];
  __shared__ float psumC[2][128];

  // XCD-bijective swizzle (2080 = 8 * 260)
  const int torig = blockIdx.x;
  const int t = (torig & 7) * (NBLK / 8) + (torig >> 3);

  // triangular decode: block t -> (bm, bn) with bm <= bn
  int bm = (int)((129.0f - sqrtf(16641.0f - 8.0f * (float)t)) * 0.5f);
  while ((bm + 1) * (129 - (bm + 1)) / 2 <= t) ++bm;
  while (bm * (129 - bm) / 2 > t) --bm;
  const int bn = bm + (t - bm * (129 - bm) / 2);
  const bool isDiag = (bm == bn);

  const int tid = threadIdx.x;
  const int lane = tid & 63, w = tid >> 6;
  const int wr = w >> 1, wc = w & 1;
  const int l31 = lane & 31, lh = lane >> 5;

  // staging (both-sides swizzle): LDS pos p holds global chunk p ^ ((row>>1)&3)
  const int srow = tid >> 2;                         // 0..63
  const int schunk = (tid & 3) ^ ((srow >> 1) & 3);
  const unsigned char* gA = Z + (size_t)(bm * 128 + srow) * D + schunk * 16;
  const unsigned char* gB = Z + (size_t)(bn * 128 + srow) * D + schunk * 16;

#define STAGE(buf)                                                \
  do {                                                            \
    gload_lds16(gA, &lA[buf][tid * 16]);                          \
    gload_lds16(gA + (size_t)64 * D, &lA[buf][tid * 16 + 4096]);  \
    gload_lds16(gB, &lB[buf][tid * 16]);                          \
    gload_lds16(gB + (size_t)64 * D, &lB[buf][tid * 16 + 4096]);  \
    gA += BK; gB += BK;                                           \
  } while (0)

  // per-lane read offsets (loop-invariant); fragment row = tile0 + l31,
  // physical bytes [lh*32, +32) as two 16B chunks, each XOR'd with the row's key
  int offA[2][2], offB[2][2];
#pragma unroll
  for (int mi = 0; mi < 2; ++mi) {
    const int rowA = wr * 64 + mi * 32 + l31;
    const int rowB = wc * 64 + mi * 32 + l31;
    const int keyA = (rowA >> 1) & 3, keyB = (rowB >> 1) & 3;
#pragma unroll
    for (int c = 0; c < 2; ++c) {
      offA[mi][c] = rowA * BK + ((lh * 2 + c) ^ keyA) * 16;
      offB[mi][c] = rowB * BK + ((lh * 2 + c) ^ keyB) * 16;
    }
  }

  f32x16 acc00 = {}, acc01 = {}, acc10 = {}, acc11 = {};

  // prologue: tile 0 staged, all waves' loads retired
  STAGE(0);
  asm volatile("s_waitcnt vmcnt(0)");
  __builtin_amdgcn_s_barrier();
  __builtin_amdgcn_sched_barrier(0);

  for (int kt = 0; kt < NKT; ++kt) {
    const int cur = kt % 3;
    if (kt + 1 < NKT) STAGE((kt + 1) % 3);   // issue early: latency hides under reads+MFMA
    __builtin_amdgcn_sched_barrier(0);       // pin stage issue before the read/MFMA region

    const unsigned char* Ab = &lA[cur][0];
    const unsigned char* Bb = &lB[cur][0];
    union { i32x4 v; long l[2]; } ra0, ra1, rb0, rb1;
    long aS[2][4], bS[2][4];
#pragma unroll
    for (int mi = 0; mi < 2; ++mi) {
      ra0.v = *(const i32x4*)(Ab + offA[mi][0]);
      ra1.v = *(const i32x4*)(Ab + offA[mi][1]);
      aS[mi][0] = ra0.l[0]; aS[mi][1] = ra0.l[1];
      aS[mi][2] = ra1.l[0]; aS[mi][3] = ra1.l[1];
    }
#pragma unroll
    for (int ni = 0; ni < 2; ++ni) {
      rb0.v = *(const i32x4*)(Bb + offB[ni][0]);
      rb1.v = *(const i32x4*)(Bb + offB[ni][1]);
      bS[ni][0] = rb0.l[0]; bS[ni][1] = rb0.l[1];
      bS[ni][2] = rb1.l[0]; bS[ni][3] = rb1.l[1];
    }

    __builtin_amdgcn_s_setprio(1);
#pragma unroll
    for (int s = 0; s < 4; ++s) {
      acc00 = __builtin_amdgcn_mfma_f32_32x32x16_fp8_fp8(aS[0][s], bS[0][s], acc00, 0, 0, 0);
      acc01 = __builtin_amdgcn_mfma_f32_32x32x16_fp8_fp8(aS[0][s], bS[1][s], acc01, 0, 0, 0);
      acc10 = __builtin_amdgcn_mfma_f32_32x32x16_fp8_fp8(aS[1][s], bS[0][s], acc10, 0, 0, 0);
      acc11 = __builtin_amdgcn_mfma_f32_32x32x16_fp8_fp8(aS[1][s], bS[1][s], acc11, 0, 0, 0);
    }
    __builtin_amdgcn_s_setprio(0);
    __builtin_amdgcn_sched_barrier(0);

    asm volatile("s_waitcnt vmcnt(0)");      // own stage of kt+1 retired (issued ~phase ago)
    __builtin_amdgcn_s_barrier();            // all waves: stages retired + reads of buf[cur] done
    __builtin_amdgcn_sched_barrier(0);
  }
#undef STAGE

  // epilogue: 32x32 C layout (r6/r7-verified): col = l31, row = (r&3) + 8*(r>>2) + 4*lh
  const int brow = bm * 128, bcol = bn * 128;
  float cs[2] = {0.f, 0.f};
#pragma unroll
  for (int mi = 0; mi < 2; ++mi) {
#pragma unroll
    for (int r = 0; r < 16; ++r) {
      const int rit = (r & 3) + 8 * (r >> 2) + 4 * lh;
      const int gq = brow + wr * 64 + mi * 32 + rit;
      const int prt = gq ^ BS;
      float sse = 0.f;
#pragma unroll
      for (int ni = 0; ni < 2; ++ni) {
        const int gc = bcol + wc * 64 + ni * 32 + l31;
        const float v = (mi == 0) ? ((ni == 0) ? acc00[r] : acc01[r])
                                  : ((ni == 0) ? acc10[r] : acc11[r]);
        if (gc == prt) { pos[gq] = v; pos[gc] = v; }   // symmetric positive pair
        const float e = (gc != gq) ? __expf(v) : 0.f;  // exclude self-term
        sse += e;
        cs[ni] += e;
      }
      sse += __shfl_xor(sse, 1);
      sse += __shfl_xor(sse, 2);
      sse += __shfl_xor(sse, 4);
      sse += __shfl_xor(sse, 8);
      sse += __shfl_xor(sse, 16);
      if (l31 == 0) psumR[wc][wr * 64 + mi * 32 + rit] = sse;
    }
  }
  if (!isDiag) {
#pragma unroll
    for (int ni = 0; ni < 2; ++ni) {
      cs[ni] += __shfl_xor(cs[ni], 32);
      if (lh == 0) psumC[wr][wc * 64 + ni * 32 + l31] = cs[ni];
    }
  }
  __syncthreads();
  if (tid < 128) atomicAdd(&sumexp[brow + tid], psumR[0][tid] + psumR[1][tid]);
  if (!isDiag && tid < 128)
    atomicAdd(&sumexp[bcol + tid], psumC[0][tid] + psumC[1][tid]);
}

// ---------------- kernel 3: final reduction + KL ----------------
__global__ __launch_bounds__(256) void finalize_kernel(
    const float* __restrict__ sumexp, const float* __restrict__ pos,
    const float* __restrict__ dio, const float* __restrict__ djo,
    float* __restrict__ out) {
  const int tid = threadIdx.x;
  float s1 = 0.f, sa = 0.f, sb = 0.f;
  for (int q = tid; q < M2; q += 256) s1 += __logf(sumexp[q]) - pos[q];
  for (int r = tid; r < BS; r += 256) { sa += __expf(dio[r]); sb += __expf(djo[r]); }

  __shared__ float red[4][3];
  float v3[3] = {s1, sa, sb};
#pragma unroll
  for (int k = 0; k < 3; ++k)
#pragma unroll
    for (int o = 32; o; o >>= 1) v3[k] += __shfl_xor(v3[k], o);
  const int w = tid >> 6, lane = tid & 63;
  if (lane == 0) { red[w][0] = v3[0]; red[w][1] = v3[1]; red[w][2] = v3[2]; }
  __syncthreads();
  const float S1 = red[0][0] + red[1][0] + red[2][0] + red[3][0];
  const float A  = red[0][1] + red[1][1] + red[2][1] + red[3][1];
  const float B  = red[0][2] + red[1][2] + red[2][2] + red[3][2];
  const float logB = __logf(B);
  const float invA = 1.0f / A;

  float kl = 0.f;
  for (int r = tid; r < BS; r += 256) {
    const float lp = djo[r] - logB;            // log_softmax target
    kl += __expf(lp) * (lp - __expf(dio[r]) * invA);
  }
#pragma unroll
  for (int o = 32; o; o >>= 1) kl += __shfl_xor(kl, o);
  __shared__ float red2[4];
  if (lane == 0) red2[w] = kl;
  __syncthreads();
  if (tid == 0) {
    const float KL = red2[0] + red2[1] + red2[2] + red2[3];
    out[0] = S1 / (float)M2 + 0.5f * KL;
  }
}

extern "C" void kernel_launch(void* const* d_in, const int* in_sizes, int n_in,
                              void* d_out, int out_size, void* d_ws, size_t ws_size,
                              hipStream_t stream) {
  const float* zi = (const float*)d_in[0];
  const float* zj = (const float*)d_in[1];
  const float* zo = (const float*)d_in[2];
  char* ws = (char*)d_ws;
  unsigned char* Z = (unsigned char*)(ws + OFF_Z);
  float* sumexp = (float*)(ws + OFF_SUMEXP);
  float* pos    = (float*)(ws + OFF_POS);
  float* dio    = (float*)(ws + OFF_DIO);
  float* djo    = (float*)(ws + OFF_DJO);

  prep_kernel<<<BS, 256, 0, stream>>>(zi, zj, zo, Z, dio, djo, sumexp);
  gemm_lse_kernel<<<NBLK, 256, 0, stream>>>(Z, sumexp, pos);
  finalize_kernel<<<1, 256, 0, stream>>>(sumexp, pos, dio, djo, (float*)d_out);
}

// Round 12
// 107.111 us; speedup vs baseline: 1.3865x; 1.0060x over previous
//
#include <hip/hip_runtime.h>
#include <hip/hip_fp8.h>

typedef int   i32x4  __attribute__((ext_vector_type(4)));
typedef float f32x16 __attribute__((ext_vector_type(16)));

#define BS 4096
#define D 1024          // elements per row; also BYTES per row in fp8
#define M2 8192

#define BK 64           // K elements (= bytes) per K-step
#define NKT (D / BK)    // 16 K-steps
#define NT 64           // M2/128 tiles per dim
#define NBLK (NT * (NT + 1) / 2)   // 2080 upper-triangle blocks (2080 % 8 == 0)

// workspace layout (bytes)
#define OFF_Z      ((size_t)0)
#define OFF_SUMEXP ((size_t)M2 * D * 2)
#define OFF_POS    (OFF_SUMEXP + (size_t)M2 * 4)
#define OFF_DIO    (OFF_POS + (size_t)M2 * 4)
#define OFF_DJO    (OFF_DIO + (size_t)BS * 4)

static __device__ __forceinline__ void gload_lds16(const void* g, void* l) {
  __builtin_amdgcn_global_load_lds(
      (__attribute__((address_space(1))) void*)(uintptr_t)g,
      (__attribute__((address_space(3))) void*)(unsigned int)(uintptr_t)l,
      16, 0, 0);
}

// ---------------- kernel 1: normalize rows, emit fp8 Z, per-row dots, zero sumexp ----------------
__global__ __launch_bounds__(256) void prep_kernel(
    const float* __restrict__ zi, const float* __restrict__ zj,
    const float* __restrict__ zo, unsigned char* __restrict__ Z,
    float* __restrict__ dio, float* __restrict__ djo,
    float* __restrict__ sumexp) {
  const int r = blockIdx.x;
  const int tid = threadIdx.x;
  if (tid < 2) sumexp[2 * r + tid] = 0.f;
  const float4 vi = ((const float4*)(zi + (size_t)r * D))[tid];
  const float4 vj = ((const float4*)(zj + (size_t)r * D))[tid];
  const float4 vo = ((const float4*)(zo + (size_t)r * D))[tid];

  float s[5];
  s[0] = vi.x * vi.x + vi.y * vi.y + vi.z * vi.z + vi.w * vi.w;
  s[1] = vj.x * vj.x + vj.y * vj.y + vj.z * vj.z + vj.w * vj.w;
  s[2] = vo.x * vo.x + vo.y * vo.y + vo.z * vo.z + vo.w * vo.w;
  s[3] = vi.x * vo.x + vi.y * vo.y + vi.z * vo.z + vi.w * vo.w;
  s[4] = vj.x * vo.x + vj.y * vo.y + vj.z * vo.z + vj.w * vo.w;

#pragma unroll
  for (int k = 0; k < 5; ++k)
#pragma unroll
    for (int o = 32; o; o >>= 1) s[k] += __shfl_xor(s[k], o);

  __shared__ float red[4][5];
  const int w = tid >> 6, lane = tid & 63;
  if (lane == 0) {
#pragma unroll
    for (int k = 0; k < 5; ++k) red[w][k] = s[k];
  }
  __syncthreads();
  float tot[5];
#pragma unroll
  for (int k = 0; k < 5; ++k)
    tot[k] = red[0][k] + red[1][k] + red[2][k] + red[3][k];

  const float rsi = 1.0f / sqrtf(tot[0]);
  const float rsj = 1.0f / sqrtf(tot[1]);
  const float rso = 1.0f / sqrtf(tot[2]);

  uchar4 oi, oj;
  oi.x = __hip_fp8_e4m3(vi.x * rsi).__x;
  oi.y = __hip_fp8_e4m3(vi.y * rsi).__x;
  oi.z = __hip_fp8_e4m3(vi.z * rsi).__x;
  oi.w = __hip_fp8_e4m3(vi.w * rsi).__x;
  oj.x = __hip_fp8_e4m3(vj.x * rsj).__x;
  oj.y = __hip_fp8_e4m3(vj.y * rsj).__x;
  oj.z = __hip_fp8_e4m3(vj.z * rsj).__x;
  oj.w = __hip_fp8_e4m3(vj.w * rsj).__x;
  ((uchar4*)(Z + (size_t)r * D))[tid] = oi;
  ((uchar4*)(Z + (size_t)(BS + r) * D))[tid] = oj;

  if (tid == 0) {
    dio[r] = tot[3] * rsi * rso;
    djo[r] = tot[4] * rsj * rso;
  }
}

// ---------------- kernel 2: upper-triangle S = Z Z^T, fp8 32x32x16 (AGPR acc), depth-2 ----------------
// r8 structure (best verified): 128x128 tile, 4 waves as 2x2, wave-tile 64x64 = 2x2 of 32x32,
// BK=64 (4 K-slices per step), 3 LDS buffers, depth-2 prefetch, counted vmcnt(8/4/0),
// 2 barriers per K-step, (row>>1)&3 16B-chunk swizzle applied both-sides.
__global__ __launch_bounds__(256) void gemm_lse_kernel(
    const unsigned char* __restrict__ Z,
    float* __restrict__ sumexp, float* __restrict__ pos) {
  __shared__ __align__(16) unsigned char lA[3][128 * BK];   // 3 x 8 KB
  __shared__ __align__(16) unsigned char lB[3][128 * BK];
  __shared__ float psumR[2][128];
  __shared__ float psumC[2][128];

  // XCD-bijective swizzle (2080 = 8 * 260)
  const int torig = blockIdx.x;
  const int t = (torig & 7) * (NBLK / 8) + (torig >> 3);

  // triangular decode: block t -> (bm, bn) with bm <= bn
  int bm = (int)((129.0f - sqrtf(16641.0f - 8.0f * (float)t)) * 0.5f);
  while ((bm + 1) * (129 - (bm + 1)) / 2 <= t) ++bm;
  while (bm * (129 - bm) / 2 > t) --bm;
  const int bn = bm + (t - bm * (129 - bm) / 2);
  const bool isDiag = (bm == bn);

  const int tid = threadIdx.x;
  const int lane = tid & 63, w = tid >> 6;
  const int wr = w >> 1, wc = w & 1;
  const int l31 = lane & 31, lh = lane >> 5;

  // staging (both-sides swizzle): LDS pos p holds global chunk p ^ ((row>>1)&3)
  const int srow = tid >> 2;                         // 0..63
  const int schunk = (tid & 3) ^ ((srow >> 1) & 3);
  const unsigned char* gA = Z + (size_t)(bm * 128 + srow) * D + schunk * 16;
  const unsigned char* gB = Z + (size_t)(bn * 128 + srow) * D + schunk * 16;

#define STAGE(buf)                                                \
  do {                                                            \
    gload_lds16(gA, &lA[buf][tid * 16]);                          \
    gload_lds16(gA + (size_t)64 * D, &lA[buf][tid * 16 + 4096]);  \
    gload_lds16(gB, &lB[buf][tid * 16]);                          \
    gload_lds16(gB + (size_t)64 * D, &lB[buf][tid * 16 + 4096]);  \
    gA += BK; gB += BK;                                           \
  } while (0)

  // per-lane read offsets (loop-invariant); fragment row = tile0 + l31,
  // physical bytes [lh*32, +32) as two 16B chunks, each XOR'd with the row's key
  int offA[2][2], offB[2][2];
#pragma unroll
  for (int mi = 0; mi < 2; ++mi) {
    const int rowA = wr * 64 + mi * 32 + l31;
    const int rowB = wc * 64 + mi * 32 + l31;
    const int keyA = (rowA >> 1) & 3, keyB = (rowB >> 1) & 3;
#pragma unroll
    for (int c = 0; c < 2; ++c) {
      offA[mi][c] = rowA * BK + ((lh * 2 + c) ^ keyA) * 16;
      offB[mi][c] = rowB * BK + ((lh * 2 + c) ^ keyB) * 16;
    }
  }

  f32x16 acc00 = {}, acc01 = {}, acc10 = {}, acc11 = {};

  STAGE(0);   // tile 0: 4 loads in flight
  STAGE(1);   // tile 1: 8 in flight

  for (int kt = 0; kt < NKT; ++kt) {
    const int cur = kt % 3;
    if (kt < NKT - 2) {
      STAGE((kt + 2) % 3);                  // 12 outstanding
      asm volatile("s_waitcnt vmcnt(8)");   // tile-kt's 4 loads complete
    } else if (kt == NKT - 2) {
      asm volatile("s_waitcnt vmcnt(4)");
    } else {
      asm volatile("s_waitcnt vmcnt(0)");
    }
    __builtin_amdgcn_s_barrier();
    __builtin_amdgcn_sched_barrier(0);

    const unsigned char* Ab = &lA[cur][0];
    const unsigned char* Bb = &lB[cur][0];
    union { i32x4 v; long l[2]; } ra0, ra1, rb0, rb1;
    long aS[2][4], bS[2][4];
#pragma unroll
    for (int mi = 0; mi < 2; ++mi) {
      ra0.v = *(const i32x4*)(Ab + offA[mi][0]);
      ra1.v = *(const i32x4*)(Ab + offA[mi][1]);
      aS[mi][0] = ra0.l[0]; aS[mi][1] = ra0.l[1];
      aS[mi][2] = ra1.l[0]; aS[mi][3] = ra1.l[1];
    }
#pragma unroll
    for (int ni = 0; ni < 2; ++ni) {
      rb0.v = *(const i32x4*)(Bb + offB[ni][0]);
      rb1.v = *(const i32x4*)(Bb + offB[ni][1]);
      bS[ni][0] = rb0.l[0]; bS[ni][1] = rb0.l[1];
      bS[ni][2] = rb1.l[0]; bS[ni][3] = rb1.l[1];
    }

    __builtin_amdgcn_s_setprio(1);
#pragma unroll
    for (int s = 0; s < 4; ++s) {
      acc00 = __builtin_amdgcn_mfma_f32_32x32x16_fp8_fp8(aS[0][s], bS[0][s], acc00, 0, 0, 0);
      acc01 = __builtin_amdgcn_mfma_f32_32x32x16_fp8_fp8(aS[0][s], bS[1][s], acc01, 0, 0, 0);
      acc10 = __builtin_amdgcn_mfma_f32_32x32x16_fp8_fp8(aS[1][s], bS[0][s], acc10, 0, 0, 0);
      acc11 = __builtin_amdgcn_mfma_f32_32x32x16_fp8_fp8(aS[1][s], bS[1][s], acc11, 0, 0, 0);
    }
    __builtin_amdgcn_s_setprio(0);

    __builtin_amdgcn_sched_barrier(0);
    __builtin_amdgcn_s_barrier();           // all waves done reading buf[cur] -> safe to restage
  }
#undef STAGE

  // epilogue: 32x32 C layout (verified): col = l31, row = (r&3) + 8*(r>>2) + 4*lh
  const int brow = bm * 128, bcol = bn * 128;
  float cs[2] = {0.f, 0.f};
#pragma unroll
  for (int mi = 0; mi < 2; ++mi) {
#pragma unroll
    for (int r = 0; r < 16; ++r) {
      const int rit = (r & 3) + 8 * (r >> 2) + 4 * lh;
      const int gq = brow + wr * 64 + mi * 32 + rit;
      const int prt = gq ^ BS;
      float sse = 0.f;
#pragma unroll
      for (int ni = 0; ni < 2; ++ni) {
        const int gc = bcol + wc * 64 + ni * 32 + l31;
        const float v = (mi == 0) ? ((ni == 0) ? acc00[r] : acc01[r])
                                  : ((ni == 0) ? acc10[r] : acc11[r]);
        if (gc == prt) { pos[gq] = v; pos[gc] = v; }   // symmetric positive pair
        const float e = (gc != gq) ? __expf(v) : 0.f;  // exclude self-term
        sse += e;
        cs[ni] += e;
      }
      sse += __shfl_xor(sse, 1);
      sse += __shfl_xor(sse, 2);
      sse += __shfl_xor(sse, 4);
      sse += __shfl_xor(sse, 8);
      sse += __shfl_xor(sse, 16);
      if (l31 == 0) psumR[wc][wr * 64 + mi * 32 + rit] = sse;
    }
  }
  if (!isDiag) {
#pragma unroll
    for (int ni = 0; ni < 2; ++ni) {
      cs[ni] += __shfl_xor(cs[ni], 32);
      if (lh == 0) psumC[wr][wc * 64 + ni * 32 + l31] = cs[ni];
    }
  }
  __syncthreads();
  if (tid < 128) atomicAdd(&sumexp[brow + tid], psumR[0][tid] + psumR[1][tid]);
  if (!isDiag && tid < 128)
    atomicAdd(&sumexp[bcol + tid], psumC[0][tid] + psumC[1][tid]);
}

// ---------------- kernel 3: final reduction + KL ----------------
__global__ __launch_bounds__(256) void finalize_kernel(
    const float* __restrict__ sumexp, const float* __restrict__ pos,
    const float* __restrict__ dio, const float* __restrict__ djo,
    float* __restrict__ out) {
  const int tid = threadIdx.x;
  float s1 = 0.f, sa = 0.f, sb = 0.f;
  for (int q = tid; q < M2; q += 256) s1 += __logf(sumexp[q]) - pos[q];
  for (int r = tid; r < BS; r += 256) { sa += __expf(dio[r]); sb += __expf(djo[r]); }

  __shared__ float red[4][3];
  float v3[3] = {s1, sa, sb};
#pragma unroll
  for (int k = 0; k < 3; ++k)
#pragma unroll
    for (int o = 32; o; o >>= 1) v3[k] += __shfl_xor(v3[k], o);
  const int w = tid >> 6, lane = tid & 63;
  if (lane == 0) { red[w][0] = v3[0]; red[w][1] = v3[1]; red[w][2] = v3[2]; }
  __syncthreads();
  const float S1 = red[0][0] + red[1][0] + red[2][0] + red[3][0];
  const float A  = red[0][1] + red[1][1] + red[2][1] + red[3][1];
  const float B  = red[0][2] + red[1][2] + red[2][2] + red[3][2];
  const float logB = __logf(B);
  const float invA = 1.0f / A;

  float kl = 0.f;
  for (int r = tid; r < BS; r += 256) {
    const float lp = djo[r] - logB;            // log_softmax target
    kl += __expf(lp) * (lp - __expf(dio[r]) * invA);
  }
#pragma unroll
  for (int o = 32; o; o >>= 1) kl += __shfl_xor(kl, o);
  __shared__ float red2[4];
  if (lane == 0) red2[w] = kl;
  __syncthreads();
  if (tid == 0) {
    const float KL = red2[0] + red2[1] + red2[2] + red2[3];
    out[0] = S1 / (float)M2 + 0.5f * KL;
  }
}

extern "C" void kernel_launch(void* const* d_in, const int* in_sizes, int n_in,
                              void* d_out, int out_size, void* d_ws, size_t ws_size,
                              hipStream_t stream) {
  const float* zi = (const float*)d_in[0];
  const float* zj = (const float*)d_in[1];
  const float* zo = (const float*)d_in[2];
  char* ws = (char*)d_ws;
  unsigned char* Z = (unsigned char*)(ws + OFF_Z);
  float* sumexp = (float*)(ws + OFF_SUMEXP);
  float* pos    = (float*)(ws + OFF_POS);
  float* dio    = (float*)(ws + OFF_DIO);
  float* djo    = (float*)(ws + OFF_DJO);

  prep_kernel<<<BS, 256, 0, stream>>>(zi, zj, zo, Z, dio, djo, sumexp);
  gemm_lse_kernel<<<NBLK, 256, 0, stream>>>(Z, sumexp, pos);
  finalize_kernel<<<1, 256, 0, stream>>>(sumexp, pos, dio, djo, (float*)d_out);
}

// Round 13
// 104.396 us; speedup vs baseline: 1.4226x; 1.0260x over previous
//
#include <hip/hip_runtime.h>

typedef int   i32x4  __attribute__((ext_vector_type(4)));
typedef int   i32x16 __attribute__((ext_vector_type(16)));

#define BS 4096
#define D 1024          // elements per row; also BYTES per row in i8
#define M2 8192

#define BK 64           // K elements (= bytes) per K-step
#define NKT (D / BK)    // 16 K-steps
#define NT 64           // M2/128 tiles per dim
#define NBLK (NT * (NT + 1) / 2)   // 2080 upper-triangle blocks (2080 % 8 == 0)

// workspace layout (bytes)
#define OFF_Z      ((size_t)0)
#define OFF_SUMEXP ((size_t)M2 * D * 2)
#define OFF_POS    (OFF_SUMEXP + (size_t)M2 * 4)
#define OFF_DIO    (OFF_POS + (size_t)M2 * 4)
#define OFF_DJO    (OFF_DIO + (size_t)BS * 4)
#define OFF_SCL    (OFF_DJO + (size_t)BS * 4)    // per-row int8 scale, M2 floats

static __device__ __forceinline__ void gload_lds16(const void* g, void* l) {
  __builtin_amdgcn_global_load_lds(
      (__attribute__((address_space(1))) void*)(uintptr_t)g,
      (__attribute__((address_space(3))) void*)(unsigned int)(uintptr_t)l,
      16, 0, 0);
}

// ---------------- kernel 1: normalize rows, emit int8 Z + row scales, per-row dots ----------------
__global__ __launch_bounds__(256) void prep_kernel(
    const float* __restrict__ zi, const float* __restrict__ zj,
    const float* __restrict__ zo, signed char* __restrict__ Z,
    float* __restrict__ dio, float* __restrict__ djo,
    float* __restrict__ sumexp, float* __restrict__ scl) {
  const int r = blockIdx.x;
  const int tid = threadIdx.x;
  if (tid < 2) sumexp[2 * r + tid] = 0.f;
  const float4 vi = ((const float4*)(zi + (size_t)r * D))[tid];
  const float4 vj = ((const float4*)(zj + (size_t)r * D))[tid];
  const float4 vo = ((const float4*)(zo + (size_t)r * D))[tid];

  float s[5];
  s[0] = vi.x * vi.x + vi.y * vi.y + vi.z * vi.z + vi.w * vi.w;
  s[1] = vj.x * vj.x + vj.y * vj.y + vj.z * vj.z + vj.w * vj.w;
  s[2] = vo.x * vo.x + vo.y * vo.y + vo.z * vo.z + vo.w * vo.w;
  s[3] = vi.x * vo.x + vi.y * vo.y + vi.z * vo.z + vi.w * vo.w;
  s[4] = vj.x * vo.x + vj.y * vo.y + vj.z * vo.z + vj.w * vo.w;
  float mi4 = fmaxf(fmaxf(fabsf(vi.x), fabsf(vi.y)), fmaxf(fabsf(vi.z), fabsf(vi.w)));
  float mj4 = fmaxf(fmaxf(fabsf(vj.x), fabsf(vj.y)), fmaxf(fabsf(vj.z), fabsf(vj.w)));

#pragma unroll
  for (int k = 0; k < 5; ++k)
#pragma unroll
    for (int o = 32; o; o >>= 1) s[k] += __shfl_xor(s[k], o);
#pragma unroll
  for (int o = 32; o; o >>= 1) {
    mi4 = fmaxf(mi4, __shfl_xor(mi4, o));
    mj4 = fmaxf(mj4, __shfl_xor(mj4, o));
  }

  __shared__ float red[4][7];
  const int w = tid >> 6, lane = tid & 63;
  if (lane == 0) {
#pragma unroll
    for (int k = 0; k < 5; ++k) red[w][k] = s[k];
    red[w][5] = mi4;
    red[w][6] = mj4;
  }
  __syncthreads();
  float tot[5];
#pragma unroll
  for (int k = 0; k < 5; ++k)
    tot[k] = red[0][k] + red[1][k] + red[2][k] + red[3][k];
  const float mIraw = fmaxf(fmaxf(red[0][5], red[1][5]), fmaxf(red[2][5], red[3][5]));
  const float mJraw = fmaxf(fmaxf(red[0][6], red[1][6]), fmaxf(red[2][6], red[3][6]));

  const float rsi = 1.0f / sqrtf(tot[0]);
  const float rsj = 1.0f / sqrtf(tot[1]);
  const float rso = 1.0f / sqrtf(tot[2]);
  const float mI = fmaxf(mIraw * rsi, 1e-8f);   // max |normalized zi|
  const float mJ = fmaxf(mJraw * rsj, 1e-8f);
  const float qI = 127.0f / mI, qJ = 127.0f / mJ;

  char4 oi, oj;
  oi.x = (signed char)__float2int_rn(vi.x * rsi * qI);
  oi.y = (signed char)__float2int_rn(vi.y * rsi * qI);
  oi.z = (signed char)__float2int_rn(vi.z * rsi * qI);
  oi.w = (signed char)__float2int_rn(vi.w * rsi * qI);
  oj.x = (signed char)__float2int_rn(vj.x * rsj * qJ);
  oj.y = (signed char)__float2int_rn(vj.y * rsj * qJ);
  oj.z = (signed char)__float2int_rn(vj.z * rsj * qJ);
  oj.w = (signed char)__float2int_rn(vj.w * rsj * qJ);
  ((char4*)(Z + (size_t)r * D))[tid] = oi;
  ((char4*)(Z + (size_t)(BS + r) * D))[tid] = oj;

  if (tid == 0) {
    dio[r] = tot[3] * rsi * rso;
    djo[r] = tot[4] * rsj * rso;
    scl[r] = mI / 127.0f;          // dequant factor per row
    scl[BS + r] = mJ / 127.0f;
  }
}

// ---------------- kernel 2: upper-triangle S = Z Z^T, i8 32x32x32 (AGPR acc), depth-2 ----------------
// r8-verified structure unchanged: 128x128 tile, 4 waves 2x2, wave-tile 64x64, BK=64,
// 3 LDS buffers, depth-2 prefetch, counted vmcnt(8/4/0), 2 barriers/K-step,
// (row>>1)&3 16B-chunk swizzle both-sides. Only the MFMA dtype changes: i8 K=32 consumes
// one 16B chunk per operand -> 8 MFMA/wave-step instead of 16, identical LDS traffic.
// Swizzle cancellation: LDS pos p holds global chunk p^key; reading (lh*2+s)^key yields
// global chunk lh*2+s for EVERY row -> A/B byte->k maps identical -> dot exact.
__global__ __launch_bounds__(256) void gemm_lse_kernel(
    const signed char* __restrict__ Z, const float* __restrict__ scl,
    float* __restrict__ sumexp, float* __restrict__ pos) {
  __shared__ __align__(16) signed char lA[3][128 * BK];   // 3 x 8 KB
  __shared__ __align__(16) signed char lB[3][128 * BK];
  __shared__ float psumR[2][128];
  __shared__ float psumC[2][128];
  __shared__ float sclR[128], sclC[128];

  // XCD-bijective swizzle (2080 = 8 * 260)
  const int torig = blockIdx.x;
  const int t = (torig & 7) * (NBLK / 8) + (torig >> 3);

  // triangular decode: block t -> (bm, bn) with bm <= bn
  int bm = (int)((129.0f - sqrtf(16641.0f - 8.0f * (float)t)) * 0.5f);
  while ((bm + 1) * (129 - (bm + 1)) / 2 <= t) ++bm;
  while (bm * (129 - bm) / 2 > t) --bm;
  const int bn = bm + (t - bm * (129 - bm) / 2);
  const bool isDiag = (bm == bn);

  const int tid = threadIdx.x;
  const int lane = tid & 63, w = tid >> 6;
  const int wr = w >> 1, wc = w & 1;
  const int l31 = lane & 31, lh = lane >> 5;

  if (tid < 128) {
    sclR[tid] = scl[bm * 128 + tid];
    sclC[tid] = scl[bn * 128 + tid];
  }

  // staging (both-sides swizzle): LDS pos p holds global chunk p ^ ((row>>1)&3)
  const int srow = tid >> 2;                         // 0..63
  const int schunk = (tid & 3) ^ ((srow >> 1) & 3);
  const signed char* gA = Z + (size_t)(bm * 128 + srow) * D + schunk * 16;
  const signed char* gB = Z + (size_t)(bn * 128 + srow) * D + schunk * 16;

#define STAGE(buf)                                                \
  do {                                                            \
    gload_lds16(gA, &lA[buf][tid * 16]);                          \
    gload_lds16(gA + (size_t)64 * D, &lA[buf][tid * 16 + 4096]);  \
    gload_lds16(gB, &lB[buf][tid * 16]);                          \
    gload_lds16(gB + (size_t)64 * D, &lB[buf][tid * 16 + 4096]);  \
    gA += BK; gB += BK;                                           \
  } while (0)

  // per-lane read offsets (loop-invariant); fragment row = tile0 + l31,
  // physical bytes [lh*32, +32) as two 16B chunks, each XOR'd with the row's key
  int offA[2][2], offB[2][2];
#pragma unroll
  for (int mi = 0; mi < 2; ++mi) {
    const int rowA = wr * 64 + mi * 32 + l31;
    const int rowB = wc * 64 + mi * 32 + l31;
    const int keyA = (rowA >> 1) & 3, keyB = (rowB >> 1) & 3;
#pragma unroll
    for (int c = 0; c < 2; ++c) {
      offA[mi][c] = rowA * BK + ((lh * 2 + c) ^ keyA) * 16;
      offB[mi][c] = rowB * BK + ((lh * 2 + c) ^ keyB) * 16;
    }
  }

  i32x16 acc00 = {}, acc01 = {}, acc10 = {}, acc11 = {};

  STAGE(0);   // tile 0: 4 loads in flight
  STAGE(1);   // tile 1: 8 in flight

  for (int kt = 0; kt < NKT; ++kt) {
    const int cur = kt % 3;
    if (kt < NKT - 2) {
      STAGE((kt + 2) % 3);                  // 12 outstanding
      asm volatile("s_waitcnt vmcnt(8)");   // tile-kt's 4 loads complete
    } else if (kt == NKT - 2) {
      asm volatile("s_waitcnt vmcnt(4)");
    } else {
      asm volatile("s_waitcnt vmcnt(0)");
    }
    __builtin_amdgcn_s_barrier();
    __builtin_amdgcn_sched_barrier(0);

    const signed char* Ab = &lA[cur][0];
    const signed char* Bb = &lB[cur][0];
    i32x4 aQ[2][2], bQ[2][2];
#pragma unroll
    for (int mi = 0; mi < 2; ++mi) {
      aQ[mi][0] = *(const i32x4*)(Ab + offA[mi][0]);
      aQ[mi][1] = *(const i32x4*)(Ab + offA[mi][1]);
    }
#pragma unroll
    for (int ni = 0; ni < 2; ++ni) {
      bQ[ni][0] = *(const i32x4*)(Bb + offB[ni][0]);
      bQ[ni][1] = *(const i32x4*)(Bb + offB[ni][1]);
    }

    __builtin_amdgcn_s_setprio(1);
#pragma unroll
    for (int s = 0; s < 2; ++s) {
      acc00 = __builtin_amdgcn_mfma_i32_32x32x32_i8(aQ[0][s], bQ[0][s], acc00, 0, 0, 0);
      acc01 = __builtin_amdgcn_mfma_i32_32x32x32_i8(aQ[0][s], bQ[1][s], acc01, 0, 0, 0);
      acc10 = __builtin_amdgcn_mfma_i32_32x32x32_i8(aQ[1][s], bQ[0][s], acc10, 0, 0, 0);
      acc11 = __builtin_amdgcn_mfma_i32_32x32x32_i8(aQ[1][s], bQ[1][s], acc11, 0, 0, 0);
    }
    __builtin_amdgcn_s_setprio(0);

    __builtin_amdgcn_sched_barrier(0);
    __builtin_amdgcn_s_barrier();           // all waves done reading buf[cur] -> safe to restage
  }
#undef STAGE

  // epilogue: 32x32 C layout (verified): col = l31, row = (r&3) + 8*(r>>2) + 4*lh
  const int brow = bm * 128, bcol = bn * 128;
  float cs[2] = {0.f, 0.f};
#pragma unroll
  for (int mi = 0; mi < 2; ++mi) {
#pragma unroll
    for (int r = 0; r < 16; ++r) {
      const int rit = (r & 3) + 8 * (r >> 2) + 4 * lh;
      const int rowL = wr * 64 + mi * 32 + rit;
      const int gq = brow + rowL;
      const int prt = gq ^ BS;
      const float sr = sclR[rowL];
      float sse = 0.f;
#pragma unroll
      for (int ni = 0; ni < 2; ++ni) {
        const int colL = wc * 64 + ni * 32 + l31;
        const int gc = bcol + colL;
        const int ai = (mi == 0) ? ((ni == 0) ? acc00[r] : acc01[r])
                                 : ((ni == 0) ? acc10[r] : acc11[r]);
        const float v = (float)ai * sr * sclC[colL];
        if (gc == prt) { pos[gq] = v; pos[gc] = v; }   // symmetric positive pair
        const float e = (gc != gq) ? __expf(v) : 0.f;  // exclude self-term
        sse += e;
        cs[ni] += e;
      }
      sse += __shfl_xor(sse, 1);
      sse += __shfl_xor(sse, 2);
      sse += __shfl_xor(sse, 4);
      sse += __shfl_xor(sse, 8);
      sse += __shfl_xor(sse, 16);
      if (l31 == 0) psumR[wc][rowL] = sse;
    }
  }
  if (!isDiag) {
#pragma unroll
    for (int ni = 0; ni < 2; ++ni) {
      cs[ni] += __shfl_xor(cs[ni], 32);
      if (lh == 0) psumC[wr][wc * 64 + ni * 32 + l31] = cs[ni];
    }
  }
  __syncthreads();
  if (tid < 128) atomicAdd(&sumexp[brow + tid], psumR[0][tid] + psumR[1][tid]);
  if (!isDiag && tid < 128)
    atomicAdd(&sumexp[bcol + tid], psumC[0][tid] + psumC[1][tid]);
}

// ---------------- kernel 3: final reduction + KL ----------------
__global__ __launch_bounds__(256) void finalize_kernel(
    const float* __restrict__ sumexp, const float* __restrict__ pos,
    const float* __restrict__ dio, const float* __restrict__ djo,
    float* __restrict__ out) {
  const int tid = threadIdx.x;
  float s1 = 0.f, sa = 0.f, sb = 0.f;
  for (int q = tid; q < M2; q += 256) s1 += __logf(sumexp[q]) - pos[q];
  for (int r = tid; r < BS; r += 256) { sa += __expf(dio[r]); sb += __expf(djo[r]); }

  __shared__ float red[4][3];
  float v3[3] = {s1, sa, sb};
#pragma unroll
  for (int k = 0; k < 3; ++k)
#pragma unroll
    for (int o = 32; o; o >>= 1) v3[k] += __shfl_xor(v3[k], o);
  const int w = tid >> 6, lane = tid & 63;
  if (lane == 0) { red[w][0] = v3[0]; red[w][1] = v3[1]; red[w][2] = v3[2]; }
  __syncthreads();
  const float S1 = red[0][0] + red[1][0] + red[2][0] + red[3][0];
  const float A  = red[0][1] + red[1][1] + red[2][1] + red[3][1];
  const float B  = red[0][2] + red[1][2] + red[2][2] + red[3][2];
  const float logB = __logf(B);
  const float invA = 1.0f / A;

  float kl = 0.f;
  for (int r = tid; r < BS; r += 256) {
    const float lp = djo[r] - logB;            // log_softmax target
    kl += __expf(lp) * (lp - __expf(dio[r]) * invA);
  }
#pragma unroll
  for (int o = 32; o; o >>= 1) kl += __shfl_xor(kl, o);
  __shared__ float red2[4];
  if (lane == 0) red2[w] = kl;
  __syncthreads();
  if (tid == 0) {
    const float KL = red2[0] + red2[1] + red2[2] + red2[3];
    out[0] = S1 / (float)M2 + 0.5f * KL;
  }
}

extern "C" void kernel_launch(void* const* d_in, const int* in_sizes, int n_in,
                              void* d_out, int out_size, void* d_ws, size_t ws_size,
                              hipStream_t stream) {
  const float* zi = (const float*)d_in[0];
  const float* zj = (const float*)d_in[1];
  const float* zo = (const float*)d_in[2];
  char* ws = (char*)d_ws;
  signed char* Z = (signed char*)(ws + OFF_Z);
  float* sumexp = (float*)(ws + OFF_SUMEXP);
  float* pos    = (float*)(ws + OFF_POS);
  float* dio    = (float*)(ws + OFF_DIO);
  float* djo    = (float*)(ws + OFF_DJO);
  float* scl    = (float*)(ws + OFF_SCL);

  prep_kernel<<<BS, 256, 0, stream>>>(zi, zj, zo, Z, dio, djo, sumexp, scl);
  gemm_lse_kernel<<<NBLK, 256, 0, stream>>>(Z, scl, sumexp, pos);
  finalize_kernel<<<1, 256, 0, stream>>>(sumexp, pos, dio, djo, (float*)d_out);
}